// Round 1
// baseline (4834.727 us; speedup 1.0000x reference)
//
#include <hip/hip_runtime.h>
#include <cstdint>
#include <cstddef>

#define HDIM 128
#define DDIM 64
#define NTYPES 5
#define NGRAPHS 16
#define POOL_P 16

static __device__ __forceinline__ float silu_f(float v) {
    return v / (1.0f + __expf(-v));
}

static __device__ __forceinline__ float4 ld4(const float* p) {
    return *reinterpret_cast<const float4*>(p);
}

// a += dot(v0v1, w[0..7])
static __device__ __forceinline__ void fma8(float& a, const float4 v0, const float4 v1,
                                            const float* __restrict__ w) {
    a = fmaf(v0.x, w[0], a);
    a = fmaf(v0.y, w[1], a);
    a = fmaf(v0.z, w[2], a);
    a = fmaf(v0.w, w[3], a);
    a = fmaf(v1.x, w[4], a);
    a = fmaf(v1.y, w[5], a);
    a = fmaf(v1.z, w[6], a);
    a = fmaf(v1.w, w[7], a);
}

// dst[j*K + k] = src[k*N + j]
__global__ void __launch_bounds__(256) transpose_k(const float* __restrict__ src,
                                                   float* __restrict__ dst, int K, int N) {
    int i = blockIdx.x * 256 + threadIdx.x;
    if (i < K * N) {
        int k = i / N, j = i - k * N;
        dst[j * K + k] = src[i];
    }
}

__global__ void __launch_bounds__(256) deg_k(const int* __restrict__ bdst,
                                             float* __restrict__ deg, int BE) {
    int i = blockIdx.x * 256 + threadIdx.x;
    if (i < BE)
        __hip_atomic_fetch_add(&deg[bdst[i]], 1.0f, __ATOMIC_RELAXED, __HIP_MEMORY_SCOPE_AGENT);
}

// One thread per edge e: x[e] = silu(concat(hi,hj) @ iw1 + b1) @ iw2 + b2 ; bt[e] classify.
__global__ void __launch_bounds__(256) bond_init_k(
    const float* __restrict__ AF, const int* __restrict__ row, const int* __restrict__ col,
    const float* __restrict__ w1t /*[64][256]*/, const float* __restrict__ b1,
    const float* __restrict__ w2 /*[64][64] orig*/, const float* __restrict__ b2,
    float* __restrict__ x, int* __restrict__ bt, int E) {
    int e = blockIdx.x * 256 + threadIdx.x;
    if (e >= E) return;
    const float* hi = AF + (size_t)row[e] * HDIM;
    const float* hj = AF + (size_t)col[e] * HDIM;

    // cosine similarity -> bond type
    float dot = 0.f, ni = 0.f, nj = 0.f;
    #pragma unroll 4
    for (int k = 0; k < HDIM; k += 4) {
        float4 a = ld4(hi + k), b = ld4(hj + k);
        dot += a.x * b.x + a.y * b.y + a.z * b.z + a.w * b.w;
        ni  += a.x * a.x + a.y * a.y + a.z * a.z + a.w * a.w;
        nj  += b.x * b.x + b.y * b.y + b.z * b.z + b.w * b.w;
    }
    float sim = dot / (fmaxf(sqrtf(ni), 1e-8f) * fmaxf(sqrtf(nj), 1e-8f));
    int t = 0;
    if (sim > 0.8f) t = 1;
    if (sim > 0.9f) t = 2;
    if (sim < 0.3f) t = 3;
    bt[e] = t;

    float acc[DDIM];
    #pragma unroll
    for (int j = 0; j < DDIM; ++j) acc[j] = b1[j];
    #pragma unroll 1
    for (int c = 0; c < 32; ++c) {          // K = 256 in chunks of 8
        const float* sp = (c < 16) ? (hi + c * 8) : (hj + (c - 16) * 8);
        float4 v0 = ld4(sp), v1 = ld4(sp + 4);
        const float* wb = w1t + c * 8;
        #pragma unroll
        for (int j = 0; j < DDIM; ++j) fma8(acc[j], v0, v1, wb + j * 256);
    }
    float o[DDIM];
    #pragma unroll
    for (int j = 0; j < DDIM; ++j) o[j] = b2[j];
    #pragma unroll
    for (int k = 0; k < DDIM; ++k) {        // layer 2, k-outer, orig-layout w2
        float hk = silu_f(acc[k]);
        const float* wk = w2 + k * DDIM;
        #pragma unroll
        for (int j = 0; j < DDIM; ++j) o[j] = fmaf(hk, wk[j], o[j]);
    }
    float* xr = x + (size_t)e * DDIM;
    #pragma unroll
    for (int j = 0; j < DDIM; ++j) xr[j] = o[j];
}

// One thread per bond-graph edge: msg = MLP([x[d], x[s], te[d]]); atomicAdd into aggr[d].
__global__ void __launch_bounds__(256) message_k(
    const float* __restrict__ x, const int* __restrict__ bsrc, const int* __restrict__ bdst,
    const int* __restrict__ bt, const float* __restrict__ embl,
    const float* __restrict__ w1t /*[64][192]*/, const float* __restrict__ b1,
    const float* __restrict__ w2 /*[64][64] orig*/, const float* __restrict__ b2,
    float* __restrict__ aggr, int BE) {
    int i = blockIdx.x * 256 + threadIdx.x;
    if (i >= BE) return;
    int s = bsrc[i], d = bdst[i];
    const float* xd = x + (size_t)d * DDIM;
    const float* xs = x + (size_t)s * DDIM;
    const float* te = embl + (size_t)bt[d] * DDIM;

    float acc[DDIM];
    #pragma unroll
    for (int j = 0; j < DDIM; ++j) acc[j] = b1[j];
    #pragma unroll 1
    for (int c = 0; c < 24; ++c) {          // K = 192 in chunks of 8
        const float* sp;
        if (c < 8)       sp = xd + c * 8;
        else if (c < 16) sp = xs + (c - 8) * 8;
        else             sp = te + (c - 16) * 8;
        float4 v0 = ld4(sp), v1 = ld4(sp + 4);
        const float* wb = w1t + c * 8;
        #pragma unroll
        for (int j = 0; j < DDIM; ++j) fma8(acc[j], v0, v1, wb + j * 192);
    }
    float o[DDIM];
    #pragma unroll
    for (int j = 0; j < DDIM; ++j) o[j] = b2[j];
    #pragma unroll
    for (int k = 0; k < DDIM; ++k) {
        float hk = silu_f(acc[k]);
        const float* wk = w2 + k * DDIM;
        #pragma unroll
        for (int j = 0; j < DDIM; ++j) o[j] = fmaf(hk, wk[j], o[j]);
    }
    float* ar = aggr + (size_t)d * DDIM;
    #pragma unroll
    for (int j = 0; j < DDIM; ++j)
        __hip_atomic_fetch_add(ar + j, o[j], __ATOMIC_RELAXED, __HIP_MEMORY_SCOPE_AGENT);
}

// One thread per edge e: x[e] += MLP([aggr[e]/denom, x[e]])
__global__ void __launch_bounds__(256) update_k(
    float* __restrict__ x, const float* __restrict__ aggr, const float* __restrict__ deg,
    const float* __restrict__ w1t /*[64][128]*/, const float* __restrict__ b1,
    const float* __restrict__ w2 /*[64][64] orig*/, const float* __restrict__ b2, int E) {
    int e = blockIdx.x * 256 + threadIdx.x;
    if (e >= E) return;
    float inv = 1.0f / fmaxf(deg[e], 1.0f);
    const float* ar = aggr + (size_t)e * DDIM;
    const float* xr = x + (size_t)e * DDIM;

    float acc[DDIM];
    #pragma unroll
    for (int j = 0; j < DDIM; ++j) acc[j] = b1[j];
    #pragma unroll 1
    for (int c = 0; c < 16; ++c) {          // K = 128 in chunks of 8
        const float* sp = (c < 8) ? (ar + c * 8) : (xr + (c - 8) * 8);
        float sc = (c < 8) ? inv : 1.0f;
        float4 v0 = ld4(sp), v1 = ld4(sp + 4);
        v0.x *= sc; v0.y *= sc; v0.z *= sc; v0.w *= sc;
        v1.x *= sc; v1.y *= sc; v1.z *= sc; v1.w *= sc;
        const float* wb = w1t + c * 8;
        #pragma unroll
        for (int j = 0; j < DDIM; ++j) fma8(acc[j], v0, v1, wb + j * 128);
    }
    float o[DDIM];
    #pragma unroll
    for (int j = 0; j < DDIM; ++j) o[j] = b2[j];
    #pragma unroll
    for (int k = 0; k < DDIM; ++k) {
        float hk = silu_f(acc[k]);
        const float* wk = w2 + k * DDIM;
        #pragma unroll
        for (int j = 0; j < DDIM; ++j) o[j] = fmaf(hk, wk[j], o[j]);
    }
    float* xw = x + (size_t)e * DDIM;
    #pragma unroll
    for (int j = 0; j < DDIM; ++j) xw[j] = xr[j] + o[j];
}

static __device__ __forceinline__ int lower_bound_bb(const int* __restrict__ row,
                                                     const int* __restrict__ batch,
                                                     int E, int g) {
    int lo = 0, hi = E;
    while (lo < hi) {
        int m = (lo + hi) >> 1;
        if (batch[row[m]] < g) lo = m + 1; else hi = m;
    }
    return lo;
}

// grid (NGRAPHS, POOL_P), block 64: partial sums -> atomicAdd into gfeat (pre-zeroed)
__global__ void __launch_bounds__(64) pool_partial_k(
    const float* __restrict__ x, const int* __restrict__ row, const int* __restrict__ batch,
    float* __restrict__ gfeat, int E) {
    int g = blockIdx.x, p = blockIdx.y, j = threadIdx.x;
    int s = lower_bound_bb(row, batch, E, g);
    int t = lower_bound_bb(row, batch, E, g + 1);
    int cnt = t - s;
    int chunk = (cnt + POOL_P - 1) / POOL_P;
    int e0 = s + p * chunk;
    int e1 = min(e0 + chunk, t);
    float sum = 0.f;
    for (int e = e0; e < e1; ++e) sum += x[(size_t)e * DDIM + j];
    if (e0 < e1)
        __hip_atomic_fetch_add(&gfeat[g * DDIM + j], sum, __ATOMIC_RELAXED,
                               __HIP_MEMORY_SCOPE_AGENT);
}

__global__ void __launch_bounds__(64) pool_final_k(
    const int* __restrict__ row, const int* __restrict__ batch,
    float* __restrict__ gfeat, int E) {
    int g = blockIdx.x, j = threadIdx.x;
    int s = lower_bound_bb(row, batch, E, g);
    int t = lower_bound_bb(row, batch, E, g + 1);
    float cnt = fmaxf((float)(t - s), 1.0f);
    gfeat[g * DDIM + j] /= cnt;
}

extern "C" void kernel_launch(void* const* d_in, const int* in_sizes, int n_in,
                              void* d_out, int out_size, void* d_ws, size_t ws_size,
                              hipStream_t stream) {
    (void)n_in; (void)out_size; (void)ws_size;
    const float* AF   = (const float*)d_in[0];
    const int*   batch = (const int*)d_in[3];
    const int*   edge_index = (const int*)d_in[4];
    const int*   bond_edge_index = (const int*)d_in[5];
    const float* iw1 = (const float*)d_in[6];
    const float* ib1 = (const float*)d_in[7];
    const float* iw2 = (const float*)d_in[8];
    const float* ib2 = (const float*)d_in[9];
    const float* emb = (const float*)d_in[10];
    const float* mw1 = (const float*)d_in[11];
    const float* mb1 = (const float*)d_in[12];
    const float* mw2 = (const float*)d_in[13];
    const float* mb2 = (const float*)d_in[14];
    const float* uw1 = (const float*)d_in[15];
    const float* ub1 = (const float*)d_in[16];
    const float* uw2 = (const float*)d_in[17];
    const float* ub2 = (const float*)d_in[18];

    const int E  = in_sizes[4] / 2;
    const int BE = in_sizes[5] / 2;

    float* xout  = (float*)d_out;                 // [E,64]
    float* gfeat = xout + (size_t)E * DDIM;       // [16,64]

    float* ws = (float*)d_ws;
    float* w1t_init = ws;           ws += 64 * 256;
    float* mw1t     = ws;           ws += 2 * 64 * 192;
    float* uw1t     = ws;           ws += 2 * 64 * 128;
    float* deg      = ws;           ws += E;
    int*   bt       = (int*)ws;     ws += E;
    float* aggr     = ws;           // [E,64]

    const int* row  = edge_index;
    const int* col  = edge_index + E;
    const int* bsrc = bond_edge_index;
    const int* bdst = bond_edge_index + BE;

    // weight transposes (layer-1 weights only; layer-2 used in original layout)
    transpose_k<<<(256 * 64 + 255) / 256, 256, 0, stream>>>(iw1, w1t_init, 256, 64);
    for (int l = 0; l < 2; ++l) {
        transpose_k<<<(192 * 64 + 255) / 256, 256, 0, stream>>>(
            mw1 + (size_t)l * 192 * 64, mw1t + (size_t)l * 64 * 192, 192, 64);
        transpose_k<<<(128 * 64 + 255) / 256, 256, 0, stream>>>(
            uw1 + (size_t)l * 128 * 64, uw1t + (size_t)l * 64 * 128, 128, 64);
    }

    hipMemsetAsync(deg, 0, (size_t)E * sizeof(float), stream);
    deg_k<<<(BE + 255) / 256, 256, 0, stream>>>(bdst, deg, BE);

    bond_init_k<<<(E + 255) / 256, 256, 0, stream>>>(AF, row, col, w1t_init, ib1, iw2, ib2,
                                                     xout, bt, E);

    for (int l = 0; l < 2; ++l) {
        hipMemsetAsync(aggr, 0, (size_t)E * DDIM * sizeof(float), stream);
        message_k<<<(BE + 255) / 256, 256, 0, stream>>>(
            xout, bsrc, bdst, bt, emb + (size_t)l * NTYPES * DDIM,
            mw1t + (size_t)l * 64 * 192, mb1 + l * DDIM,
            mw2 + (size_t)l * DDIM * DDIM, mb2 + l * DDIM, aggr, BE);
        update_k<<<(E + 255) / 256, 256, 0, stream>>>(
            xout, aggr, deg,
            uw1t + (size_t)l * 64 * 128, ub1 + l * DDIM,
            uw2 + (size_t)l * DDIM * DDIM, ub2 + l * DDIM, E);
    }

    hipMemsetAsync(gfeat, 0, NGRAPHS * DDIM * sizeof(float), stream);
    dim3 pg(NGRAPHS, POOL_P);
    pool_partial_k<<<pg, 64, 0, stream>>>(xout, row, batch, gfeat, E);
    pool_final_k<<<NGRAPHS, 64, 0, stream>>>(row, batch, gfeat, E);
}

// Round 2
// 1044.092 us; speedup vs baseline: 4.6306x; 4.6306x over previous
//
#include <hip/hip_runtime.h>
#include <cstdint>
#include <cstddef>

#define HDIM 128
#define DDIM 64
#define NTYPES 5
#define NGRAPHS 16
#define POOL_P 16

static __device__ __forceinline__ float silu_f(float v) {
    return v / (1.0f + __expf(-v));
}

static __device__ __forceinline__ float4 ld4(const float* p) {
    return *reinterpret_cast<const float4*>(p);
}

static __device__ __forceinline__ void st4(float* p, float4 v) {
    *reinterpret_cast<float4*>(p) = v;
}

static __device__ __forceinline__ float4 add4(float4 a, float4 b) {
    return make_float4(a.x + b.x, a.y + b.y, a.z + b.z, a.w + b.w);
}

// s += silu(v)
static __device__ __forceinline__ void silu_acc4(float4& s, float4 v) {
    s.x += silu_f(v.x);
    s.y += silu_f(v.y);
    s.z += silu_f(v.z);
    s.w += silu_f(v.w);
}

// a += dot(v0v1, w[0..7])
static __device__ __forceinline__ void fma8(float& a, const float4 v0, const float4 v1,
                                            const float* __restrict__ w) {
    a = fmaf(v0.x, w[0], a);
    a = fmaf(v0.y, w[1], a);
    a = fmaf(v0.z, w[2], a);
    a = fmaf(v0.w, w[3], a);
    a = fmaf(v1.x, w[4], a);
    a = fmaf(v1.y, w[5], a);
    a = fmaf(v1.z, w[6], a);
    a = fmaf(v1.w, w[7], a);
}

// dst[j*K + k] = src[k*N + j]
__global__ void __launch_bounds__(256) transpose_k(const float* __restrict__ src,
                                                   float* __restrict__ dst, int K, int N) {
    int i = blockIdx.x * 256 + threadIdx.x;
    if (i < K * N) {
        int k = i / N, j = i - k * N;
        dst[j * K + k] = src[i];
    }
}

__global__ void __launch_bounds__(256) count_k(const int* __restrict__ bdst,
                                               int* __restrict__ cnt, int BE) {
    int i = blockIdx.x * 256 + threadIdx.x;
    if (i < BE)
        __hip_atomic_fetch_add(&cnt[bdst[i]], 1, __ATOMIC_RELAXED, __HIP_MEMORY_SCOPE_AGENT);
}

// single-block exclusive scan of cnt[E] -> offs[E+1]
__global__ void __launch_bounds__(1024) scan_k(const int* __restrict__ cnt,
                                               int* __restrict__ offs, int E) {
    __shared__ int part[1024];
    int t = threadIdx.x;
    int chunk = (E + 1023) >> 10;
    int lo = t * chunk, hi = min(lo + chunk, E);
    int s = 0;
    for (int i = lo; i < hi; ++i) s += cnt[i];
    part[t] = s;
    __syncthreads();
    for (int off = 1; off < 1024; off <<= 1) {
        int v = (t >= off) ? part[t - off] : 0;
        __syncthreads();
        part[t] += v;
        __syncthreads();
    }
    int run = (t > 0) ? part[t - 1] : 0;
    for (int i = lo; i < hi; ++i) { offs[i] = run; run += cnt[i]; }
    if (t == 0) offs[E] = part[1023];
}

__global__ void __launch_bounds__(256) scatter_k(const int* __restrict__ bsrc,
                                                 const int* __restrict__ bdst,
                                                 int* __restrict__ cursor,
                                                 int* __restrict__ srclist, int BE) {
    int i = blockIdx.x * 256 + threadIdx.x;
    if (i < BE) {
        int d = bdst[i];
        int p = __hip_atomic_fetch_add(&cursor[d], 1, __ATOMIC_RELAXED,
                                       __HIP_MEMORY_SCOPE_AGENT);
        srclist[p] = bsrc[i];
    }
}

// One thread per edge e: x[e] = silu(concat(hi,hj) @ iw1 + b1) @ iw2 + b2 ; bt[e] classify.
__global__ void __launch_bounds__(256) bond_init_k(
    const float* __restrict__ AF, const int* __restrict__ row, const int* __restrict__ col,
    const float* __restrict__ w1t /*[64][256]*/, const float* __restrict__ b1,
    const float* __restrict__ w2 /*[64][64] orig*/, const float* __restrict__ b2,
    float* __restrict__ x, int* __restrict__ bt, int E) {
    int e = blockIdx.x * 256 + threadIdx.x;
    if (e >= E) return;
    const float* hi = AF + (size_t)row[e] * HDIM;
    const float* hj = AF + (size_t)col[e] * HDIM;

    float dot = 0.f, ni = 0.f, nj = 0.f;
    #pragma unroll 4
    for (int k = 0; k < HDIM; k += 4) {
        float4 a = ld4(hi + k), b = ld4(hj + k);
        dot += a.x * b.x + a.y * b.y + a.z * b.z + a.w * b.w;
        ni  += a.x * a.x + a.y * a.y + a.z * a.z + a.w * a.w;
        nj  += b.x * b.x + b.y * b.y + b.z * b.z + b.w * b.w;
    }
    float sim = dot / (fmaxf(sqrtf(ni), 1e-8f) * fmaxf(sqrtf(nj), 1e-8f));
    int t = 0;
    if (sim > 0.8f) t = 1;
    if (sim > 0.9f) t = 2;
    if (sim < 0.3f) t = 3;
    bt[e] = t;

    float acc[DDIM];
    #pragma unroll
    for (int j = 0; j < DDIM; ++j) acc[j] = b1[j];
    #pragma unroll 1
    for (int c = 0; c < 32; ++c) {          // K = 256 in chunks of 8
        const float* sp = (c < 16) ? (hi + c * 8) : (hj + (c - 16) * 8);
        float4 v0 = ld4(sp), v1 = ld4(sp + 4);
        const float* wb = w1t + c * 8;
        #pragma unroll
        for (int j = 0; j < DDIM; ++j) fma8(acc[j], v0, v1, wb + j * 256);
    }
    float o[DDIM];
    #pragma unroll
    for (int j = 0; j < DDIM; ++j) o[j] = b2[j];
    #pragma unroll
    for (int k = 0; k < DDIM; ++k) {
        float hk = silu_f(acc[k]);
        const float* wk = w2 + k * DDIM;
        #pragma unroll
        for (int j = 0; j < DDIM; ++j) o[j] = fmaf(hk, wk[j], o[j]);
    }
    float* xr = x + (size_t)e * DDIM;
    #pragma unroll
    for (int j = 0; j < DDIM; ++j) xr[j] = o[j];
}

// tt[t][j] = b1[j] + sum_k emb[t][k] * w1[(128+k)*64 + j]   (grid NTYPES x 64 thr)
__global__ void __launch_bounds__(64) tt_k(const float* __restrict__ embl,
                                           const float* __restrict__ w1,
                                           const float* __restrict__ b1,
                                           float* __restrict__ tt) {
    int t = blockIdx.x, j = threadIdx.x;
    float s = b1[j];
    #pragma unroll 8
    for (int k = 0; k < DDIM; ++k)
        s = fmaf(embl[t * DDIM + k], w1[(HDIM + k) * DDIM + j], s);
    tt[t * DDIM + j] = s;
}

// One thread per bond: pd[e] = x[e] @ W1[0:64], ps[e] = x[e] @ W1[64:128]  (k-outer)
__global__ void __launch_bounds__(256) proj_k(const float* __restrict__ x,
                                              const float* __restrict__ w1 /*[192][64]*/,
                                              float* __restrict__ pd, float* __restrict__ ps,
                                              int E) {
    int e = blockIdx.x * 256 + threadIdx.x;
    if (e >= E) return;
    const float* xr = x + (size_t)e * DDIM;
    float pdv[DDIM], psv[DDIM];
    #pragma unroll
    for (int j = 0; j < DDIM; ++j) { pdv[j] = 0.f; psv[j] = 0.f; }
    #pragma unroll 1
    for (int c = 0; c < 16; ++c) {
        float4 v = ld4(xr + c * 4);
        float xv[4] = {v.x, v.y, v.z, v.w};
        #pragma unroll
        for (int kk = 0; kk < 4; ++kk) {
            int k = c * 4 + kk;
            const float* wd = w1 + (size_t)k * DDIM;
            const float* wsrc = w1 + (size_t)(DDIM + k) * DDIM;
            float xk = xv[kk];
            #pragma unroll
            for (int j = 0; j < DDIM; ++j) {
                pdv[j] = fmaf(xk, wd[j], pdv[j]);
                psv[j] = fmaf(xk, wsrc[j], psv[j]);
            }
        }
    }
    float* pr = pd + (size_t)e * DDIM;
    float* qr = ps + (size_t)e * DDIM;
    #pragma unroll
    for (int j = 0; j < DDIM; ++j) { pr[j] = pdv[j]; qr[j] = psv[j]; }
}

// 4 threads per bond, 16 features each: s[d] = sum_src silu(pd[d] + tt[bt[d]] + ps[src])
// written in-place over pd.
__global__ void __launch_bounds__(256) gather_k(
    float* __restrict__ pd, const float* __restrict__ ps, const float* __restrict__ tt,
    const int* __restrict__ bt, const int* __restrict__ offs,
    const int* __restrict__ srclist, int E) {
    int tid = blockIdx.x * 256 + threadIdx.x;
    int d = tid >> 2, q = tid & 3;
    if (d >= E) return;
    int j0 = q * 16;
    float* pr = pd + (size_t)d * DDIM + j0;
    const float* tp = tt + bt[d] * DDIM + j0;
    float4 b0 = add4(ld4(pr + 0),  ld4(tp + 0));
    float4 b1 = add4(ld4(pr + 4),  ld4(tp + 4));
    float4 b2 = add4(ld4(pr + 8),  ld4(tp + 8));
    float4 b3 = add4(ld4(pr + 12), ld4(tp + 12));
    float4 s0 = make_float4(0, 0, 0, 0), s1 = s0, s2 = s0, s3 = s0;
    int p0 = offs[d], p1 = offs[d + 1];
    for (int p = p0; p < p1; ++p) {
        const float* sr = ps + (size_t)srclist[p] * DDIM + j0;
        float4 v0 = ld4(sr + 0), v1 = ld4(sr + 4), v2 = ld4(sr + 8), v3 = ld4(sr + 12);
        silu_acc4(s0, add4(b0, v0));
        silu_acc4(s1, add4(b1, v1));
        silu_acc4(s2, add4(b2, v2));
        silu_acc4(s3, add4(b3, v3));
    }
    st4(pr + 0,  s0);
    st4(pr + 4,  s1);
    st4(pr + 8,  s2);
    st4(pr + 12, s3);
}

// One thread per bond: m = (s @ W2m + deg*b2m)/max(deg,1);
// x += silu([m, x] @ Wu1 + bu1) @ Wu2 + bu2
__global__ void __launch_bounds__(256) update2_k(
    float* __restrict__ x, const float* __restrict__ s, const int* __restrict__ cnt,
    const float* __restrict__ w2m, const float* __restrict__ b2m,
    const float* __restrict__ uw1 /*[128][64]*/, const float* __restrict__ ub1,
    const float* __restrict__ uw2 /*[64][64]*/, const float* __restrict__ ub2, int E) {
    int e = blockIdx.x * 256 + threadIdx.x;
    if (e >= E) return;
    float degf = (float)cnt[e];
    float inv = 1.0f / fmaxf(degf, 1.0f);
    const float* sr = s + (size_t)e * DDIM;

    float mm[DDIM];
    #pragma unroll
    for (int j = 0; j < DDIM; ++j) mm[j] = degf * b2m[j];
    #pragma unroll 2
    for (int k = 0; k < DDIM; ++k) {
        float sk = sr[k];
        const float* wk = w2m + (size_t)k * DDIM;
        #pragma unroll
        for (int j = 0; j < DDIM; ++j) mm[j] = fmaf(sk, wk[j], mm[j]);
    }
    #pragma unroll
    for (int j = 0; j < DDIM; ++j) mm[j] *= inv;

    float acc[DDIM];
    #pragma unroll
    for (int j = 0; j < DDIM; ++j) acc[j] = ub1[j];
    #pragma unroll 2
    for (int k = 0; k < DDIM; ++k) {
        float mk = mm[k];
        const float* wk = uw1 + (size_t)k * DDIM;
        #pragma unroll
        for (int j = 0; j < DDIM; ++j) acc[j] = fmaf(mk, wk[j], acc[j]);
    }
    const float* xr = x + (size_t)e * DDIM;
    float xv[DDIM];
    #pragma unroll
    for (int j = 0; j < DDIM; ++j) xv[j] = xr[j];
    #pragma unroll 2
    for (int k = 0; k < DDIM; ++k) {
        float xk = xv[k];
        const float* wk = uw1 + (size_t)(DDIM + k) * DDIM;
        #pragma unroll
        for (int j = 0; j < DDIM; ++j) acc[j] = fmaf(xk, wk[j], acc[j]);
    }
    float o[DDIM];
    #pragma unroll
    for (int j = 0; j < DDIM; ++j) o[j] = ub2[j];
    #pragma unroll 2
    for (int k = 0; k < DDIM; ++k) {
        float hk = silu_f(acc[k]);
        const float* wk = uw2 + (size_t)k * DDIM;
        #pragma unroll
        for (int j = 0; j < DDIM; ++j) o[j] = fmaf(hk, wk[j], o[j]);
    }
    float* xw = x + (size_t)e * DDIM;
    #pragma unroll
    for (int j = 0; j < DDIM; ++j) xw[j] = xv[j] + o[j];
}

static __device__ __forceinline__ int lower_bound_bb(const int* __restrict__ row,
                                                     const int* __restrict__ batch,
                                                     int E, int g) {
    int lo = 0, hi = E;
    while (lo < hi) {
        int m = (lo + hi) >> 1;
        if (batch[row[m]] < g) lo = m + 1; else hi = m;
    }
    return lo;
}

__global__ void __launch_bounds__(64) pool_partial_k(
    const float* __restrict__ x, const int* __restrict__ row, const int* __restrict__ batch,
    float* __restrict__ gfeat, int E) {
    int g = blockIdx.x, p = blockIdx.y, j = threadIdx.x;
    int s = lower_bound_bb(row, batch, E, g);
    int t = lower_bound_bb(row, batch, E, g + 1);
    int cnt = t - s;
    int chunk = (cnt + POOL_P - 1) / POOL_P;
    int e0 = s + p * chunk;
    int e1 = min(e0 + chunk, t);
    float sum = 0.f;
    for (int e = e0; e < e1; ++e) sum += x[(size_t)e * DDIM + j];
    if (e0 < e1)
        __hip_atomic_fetch_add(&gfeat[g * DDIM + j], sum, __ATOMIC_RELAXED,
                               __HIP_MEMORY_SCOPE_AGENT);
}

__global__ void __launch_bounds__(64) pool_final_k(
    const int* __restrict__ row, const int* __restrict__ batch,
    float* __restrict__ gfeat, int E) {
    int g = blockIdx.x, j = threadIdx.x;
    int s = lower_bound_bb(row, batch, E, g);
    int t = lower_bound_bb(row, batch, E, g + 1);
    float cnt = fmaxf((float)(t - s), 1.0f);
    gfeat[g * DDIM + j] /= cnt;
}

extern "C" void kernel_launch(void* const* d_in, const int* in_sizes, int n_in,
                              void* d_out, int out_size, void* d_ws, size_t ws_size,
                              hipStream_t stream) {
    (void)n_in; (void)out_size; (void)ws_size;
    const float* AF    = (const float*)d_in[0];
    const int*   batch = (const int*)d_in[3];
    const int*   edge_index      = (const int*)d_in[4];
    const int*   bond_edge_index = (const int*)d_in[5];
    const float* iw1 = (const float*)d_in[6];
    const float* ib1 = (const float*)d_in[7];
    const float* iw2 = (const float*)d_in[8];
    const float* ib2 = (const float*)d_in[9];
    const float* emb = (const float*)d_in[10];
    const float* mw1 = (const float*)d_in[11];
    const float* mb1 = (const float*)d_in[12];
    const float* mw2 = (const float*)d_in[13];
    const float* mb2 = (const float*)d_in[14];
    const float* uw1 = (const float*)d_in[15];
    const float* ub1 = (const float*)d_in[16];
    const float* uw2 = (const float*)d_in[17];
    const float* ub2 = (const float*)d_in[18];

    const int E  = in_sizes[4] / 2;
    const int BE = in_sizes[5] / 2;

    float* xout  = (float*)d_out;                 // [E,64]
    float* gfeat = xout + (size_t)E * DDIM;       // [16,64]

    // workspace layout
    char* w = (char*)d_ws;
    float* w1t_init = (float*)w;  w += sizeof(float) * 64 * 256;
    float* tt       = (float*)w;  w += sizeof(float) * NTYPES * DDIM;
    int*   cnt      = (int*)w;    w += sizeof(int) * E;
    int*   offs     = (int*)w;    w += sizeof(int) * (E + 1);
    int*   cursor   = (int*)w;    w += sizeof(int) * E;
    int*   bt       = (int*)w;    w += sizeof(int) * E;
    int*   srclist  = (int*)w;    w += sizeof(int) * BE;
    // align to 16B for float4
    w = (char*)(((uintptr_t)w + 15) & ~(uintptr_t)15);
    float* pd       = (float*)w;  w += sizeof(float) * (size_t)E * DDIM;
    float* ps       = (float*)w;  w += sizeof(float) * (size_t)E * DDIM;

    const int* row  = edge_index;
    const int* col  = edge_index + E;
    const int* bsrc = bond_edge_index;
    const int* bdst = bond_edge_index + BE;

    // CSR build (int atomics only)
    hipMemsetAsync(cnt, 0, (size_t)E * sizeof(int), stream);
    count_k<<<(BE + 255) / 256, 256, 0, stream>>>(bdst, cnt, BE);
    scan_k<<<1, 1024, 0, stream>>>(cnt, offs, E);
    hipMemcpyAsync(cursor, offs, (size_t)E * sizeof(int), hipMemcpyDeviceToDevice, stream);
    scatter_k<<<(BE + 255) / 256, 256, 0, stream>>>(bsrc, bdst, cursor, srclist, BE);

    // bond init
    transpose_k<<<(256 * 64 + 255) / 256, 256, 0, stream>>>(iw1, w1t_init, 256, 64);
    bond_init_k<<<(E + 255) / 256, 256, 0, stream>>>(AF, row, col, w1t_init, ib1, iw2, ib2,
                                                     xout, bt, E);

    for (int l = 0; l < 2; ++l) {
        const float* w1l  = mw1 + (size_t)l * 192 * 64;
        const float* b1l  = mb1 + (size_t)l * DDIM;
        const float* w2l  = mw2 + (size_t)l * DDIM * DDIM;
        const float* b2l  = mb2 + (size_t)l * DDIM;
        const float* embl = emb + (size_t)l * NTYPES * DDIM;

        tt_k<<<NTYPES, 64, 0, stream>>>(embl, w1l, b1l, tt);
        proj_k<<<(E + 255) / 256, 256, 0, stream>>>(xout, w1l, pd, ps, E);
        gather_k<<<(E * 4 + 255) / 256, 256, 0, stream>>>(pd, ps, tt, bt, offs, srclist, E);
        update2_k<<<(E + 255) / 256, 256, 0, stream>>>(
            xout, pd, cnt, w2l, b2l,
            uw1 + (size_t)l * 128 * 64, ub1 + (size_t)l * DDIM,
            uw2 + (size_t)l * DDIM * DDIM, ub2 + (size_t)l * DDIM, E);
    }

    hipMemsetAsync(gfeat, 0, NGRAPHS * DDIM * sizeof(float), stream);
    dim3 pg(NGRAPHS, POOL_P);
    pool_partial_k<<<pg, 64, 0, stream>>>(xout, row, batch, gfeat, E);
    pool_final_k<<<NGRAPHS, 64, 0, stream>>>(row, batch, gfeat, E);
}

// Round 3
// 607.338 us; speedup vs baseline: 7.9605x; 1.7191x over previous
//
#include <hip/hip_runtime.h>
#include <cstdint>
#include <cstddef>

#define HDIM 128
#define DDIM 64
#define NTYPES 5
#define NGRAPHS 16
#define POOL_P 16
#define EPB 64   // edges per block (one per lane)

static __device__ __forceinline__ float silu_f(float v) {
    return v / (1.0f + __expf(-v));
}

static __device__ __forceinline__ float4 ld4(const float* p) {
    return *reinterpret_cast<const float4*>(p);
}

static __device__ __forceinline__ void st4(float* p, float4 v) {
    *reinterpret_cast<float4*>(p) = v;
}

static __device__ __forceinline__ float4 add4(float4 a, float4 b) {
    return make_float4(a.x + b.x, a.y + b.y, a.z + b.z, a.w + b.w);
}

static __device__ __forceinline__ void silu_acc4(float4& s, float4 v) {
    s.x += silu_f(v.x);
    s.y += silu_f(v.y);
    s.z += silu_f(v.z);
    s.w += silu_f(v.w);
}

// ---------------- CSR build ----------------
__global__ void __launch_bounds__(256) count_k(const int* __restrict__ bdst,
                                               int* __restrict__ cnt, int BE) {
    int i = blockIdx.x * 256 + threadIdx.x;
    if (i < BE)
        __hip_atomic_fetch_add(&cnt[bdst[i]], 1, __ATOMIC_RELAXED, __HIP_MEMORY_SCOPE_AGENT);
}

__global__ void __launch_bounds__(1024) scan_k(const int* __restrict__ cnt,
                                               int* __restrict__ offs, int E) {
    __shared__ int part[1024];
    int t = threadIdx.x;
    int chunk = (E + 1023) >> 10;
    int lo = t * chunk, hi = min(lo + chunk, E);
    int s = 0;
    for (int i = lo; i < hi; ++i) s += cnt[i];
    part[t] = s;
    __syncthreads();
    for (int off = 1; off < 1024; off <<= 1) {
        int v = (t >= off) ? part[t - off] : 0;
        __syncthreads();
        part[t] += v;
        __syncthreads();
    }
    int run = (t > 0) ? part[t - 1] : 0;
    for (int i = lo; i < hi; ++i) { offs[i] = run; run += cnt[i]; }
    if (t == 0) offs[E] = part[1023];
}

__global__ void __launch_bounds__(256) scatter_k(const int* __restrict__ bsrc,
                                                 const int* __restrict__ bdst,
                                                 int* __restrict__ cursor,
                                                 int* __restrict__ srclist, int BE) {
    int i = blockIdx.x * 256 + threadIdx.x;
    if (i < BE) {
        int d = bdst[i];
        int p = __hip_atomic_fetch_add(&cursor[d], 1, __ATOMIC_RELAXED,
                                       __HIP_MEMORY_SCOPE_AGENT);
        srclist[p] = bsrc[i];
    }
}

// ---------------- bond init: wave-sliced ----------------
// block = 4 waves x 64 lanes; lane = edge (64 edges/block); wave w owns outputs [16w,16w+16)
__global__ void __launch_bounds__(256) bond_init_k(
    const float* __restrict__ AF, const int* __restrict__ row, const int* __restrict__ col,
    const float* __restrict__ w1 /*[256][64]*/, const float* __restrict__ b1,
    const float* __restrict__ w2 /*[64][64]*/, const float* __restrict__ b2,
    float* __restrict__ x, int* __restrict__ bt, int E) {
    __shared__ float hbuf[EPB][DDIM + 1];
    int lane = threadIdx.x & 63;
    int w = __builtin_amdgcn_readfirstlane((int)(threadIdx.x >> 6));
    int e = blockIdx.x * EPB + lane;
    bool ok = e < E;
    int eidx = ok ? e : 0;
    const float* hi = AF + (size_t)row[eidx] * HDIM;
    const float* hj = AF + (size_t)col[eidx] * HDIM;
    int j0 = w * 16;

    if (w == 0) {
        float dot = 0.f, ni = 0.f, nj = 0.f;
        #pragma unroll 4
        for (int k = 0; k < HDIM; k += 4) {
            float4 a = ld4(hi + k), b = ld4(hj + k);
            dot += a.x * b.x + a.y * b.y + a.z * b.z + a.w * b.w;
            ni  += a.x * a.x + a.y * a.y + a.z * a.z + a.w * a.w;
            nj  += b.x * b.x + b.y * b.y + b.z * b.z + b.w * b.w;
        }
        float sim = dot / (fmaxf(sqrtf(ni), 1e-8f) * fmaxf(sqrtf(nj), 1e-8f));
        int t = 0;
        if (sim > 0.8f) t = 1;
        if (sim > 0.9f) t = 2;
        if (sim < 0.3f) t = 3;
        if (ok) bt[e] = t;
    }

    float acc[16];
    #pragma unroll
    for (int jj = 0; jj < 16; ++jj) acc[jj] = b1[j0 + jj];
    #pragma unroll 2
    for (int c = 0; c < 32; ++c) {          // K = 256 in chunks of 8
        const float* sp = (c < 16) ? (hi + c * 8) : (hj + (c - 16) * 8);
        float4 v0 = ld4(sp), v1 = ld4(sp + 4);
        float xv[8] = {v0.x, v0.y, v0.z, v0.w, v1.x, v1.y, v1.z, v1.w};
        const float* wb = w1 + (size_t)(c * 8) * DDIM + j0;
        #pragma unroll
        for (int kk = 0; kk < 8; ++kk) {
            const float* wk = wb + (size_t)kk * DDIM;
            #pragma unroll
            for (int jj = 0; jj < 16; ++jj) acc[jj] = fmaf(xv[kk], wk[jj], acc[jj]);
        }
    }
    #pragma unroll
    for (int jj = 0; jj < 16; ++jj) hbuf[lane][j0 + jj] = silu_f(acc[jj]);
    __syncthreads();

    float o[16];
    #pragma unroll
    for (int jj = 0; jj < 16; ++jj) o[jj] = b2[j0 + jj];
    #pragma unroll 4
    for (int k = 0; k < DDIM; ++k) {
        float hk = hbuf[lane][k];
        const float* wk = w2 + (size_t)k * DDIM + j0;
        #pragma unroll
        for (int jj = 0; jj < 16; ++jj) o[jj] = fmaf(hk, wk[jj], o[jj]);
    }
    if (ok) {
        float* xr = x + (size_t)e * DDIM + j0;
        st4(xr + 0,  make_float4(o[0],  o[1],  o[2],  o[3]));
        st4(xr + 4,  make_float4(o[4],  o[5],  o[6],  o[7]));
        st4(xr + 8,  make_float4(o[8],  o[9],  o[10], o[11]));
        st4(xr + 12, make_float4(o[12], o[13], o[14], o[15]));
    }
}

// tt[t][j] = b1[j] + sum_k emb[t][k] * w1[(128+k)*64 + j]
__global__ void __launch_bounds__(64) tt_k(const float* __restrict__ embl,
                                           const float* __restrict__ w1,
                                           const float* __restrict__ b1,
                                           float* __restrict__ tt) {
    int t = blockIdx.x, j = threadIdx.x;
    float s = b1[j];
    #pragma unroll 8
    for (int k = 0; k < DDIM; ++k)
        s = fmaf(embl[t * DDIM + k], w1[(HDIM + k) * DDIM + j], s);
    tt[t * DDIM + j] = s;
}

// proj: wave-sliced. pd[e][j0+jj] = x[e]@W1[0:64]; ps = x[e]@W1[64:128]
__global__ void __launch_bounds__(256) proj_k(const float* __restrict__ x,
                                              const float* __restrict__ w1 /*[192][64]*/,
                                              float* __restrict__ pd, float* __restrict__ ps,
                                              int E) {
    int lane = threadIdx.x & 63;
    int w = __builtin_amdgcn_readfirstlane((int)(threadIdx.x >> 6));
    int e = blockIdx.x * EPB + lane;
    bool ok = e < E;
    int eidx = ok ? e : 0;
    int j0 = w * 16;
    const float* xr = x + (size_t)eidx * DDIM;

    float apd[16], aps[16];
    #pragma unroll
    for (int jj = 0; jj < 16; ++jj) { apd[jj] = 0.f; aps[jj] = 0.f; }
    #pragma unroll 2
    for (int c = 0; c < 16; ++c) {          // K = 64 in chunks of 4
        float4 v = ld4(xr + c * 4);
        float xv[4] = {v.x, v.y, v.z, v.w};
        #pragma unroll
        for (int kk = 0; kk < 4; ++kk) {
            int k = c * 4 + kk;
            const float* wd = w1 + (size_t)k * DDIM + j0;
            const float* wsv = w1 + (size_t)(DDIM + k) * DDIM + j0;
            #pragma unroll
            for (int jj = 0; jj < 16; ++jj) {
                apd[jj] = fmaf(xv[kk], wd[jj], apd[jj]);
                aps[jj] = fmaf(xv[kk], wsv[jj], aps[jj]);
            }
        }
    }
    if (ok) {
        float* pr = pd + (size_t)e * DDIM + j0;
        float* qr = ps + (size_t)e * DDIM + j0;
        st4(pr + 0,  make_float4(apd[0],  apd[1],  apd[2],  apd[3]));
        st4(pr + 4,  make_float4(apd[4],  apd[5],  apd[6],  apd[7]));
        st4(pr + 8,  make_float4(apd[8],  apd[9],  apd[10], apd[11]));
        st4(pr + 12, make_float4(apd[12], apd[13], apd[14], apd[15]));
        st4(qr + 0,  make_float4(aps[0],  aps[1],  aps[2],  aps[3]));
        st4(qr + 4,  make_float4(aps[4],  aps[5],  aps[6],  aps[7]));
        st4(qr + 8,  make_float4(aps[8],  aps[9],  aps[10], aps[11]));
        st4(qr + 12, make_float4(aps[12], aps[13], aps[14], aps[15]));
    }
}

// 4 threads per bond, 16 features each: s[d] = sum_src silu(pd[d] + tt[bt[d]] + ps[src])
__global__ void __launch_bounds__(256) gather_k(
    float* __restrict__ pd, const float* __restrict__ ps, const float* __restrict__ tt,
    const int* __restrict__ bt, const int* __restrict__ offs,
    const int* __restrict__ srclist, int E) {
    int tid = blockIdx.x * 256 + threadIdx.x;
    int d = tid >> 2, q = tid & 3;
    if (d >= E) return;
    int j0 = q * 16;
    float* pr = pd + (size_t)d * DDIM + j0;
    const float* tp = tt + bt[d] * DDIM + j0;
    float4 b0 = add4(ld4(pr + 0),  ld4(tp + 0));
    float4 b1 = add4(ld4(pr + 4),  ld4(tp + 4));
    float4 b2 = add4(ld4(pr + 8),  ld4(tp + 8));
    float4 b3 = add4(ld4(pr + 12), ld4(tp + 12));
    float4 s0 = make_float4(0, 0, 0, 0), s1 = s0, s2 = s0, s3 = s0;
    int p0 = offs[d], p1 = offs[d + 1];
    for (int p = p0; p < p1; ++p) {
        const float* sr = ps + (size_t)srclist[p] * DDIM + j0;
        float4 v0 = ld4(sr + 0), v1 = ld4(sr + 4), v2 = ld4(sr + 8), v3 = ld4(sr + 12);
        silu_acc4(s0, add4(b0, v0));
        silu_acc4(s1, add4(b1, v1));
        silu_acc4(s2, add4(b2, v2));
        silu_acc4(s3, add4(b3, v3));
    }
    st4(pr + 0,  s0);
    st4(pr + 4,  s1);
    st4(pr + 8,  s2);
    st4(pr + 12, s3);
}

// update: wave-sliced, 3 chained matmuls with LDS handoffs.
// mm = (s@W2m + deg*b2m)/max(deg,1);  x += silu([mm,x]@Wu1 + bu1)@Wu2 + bu2
__global__ void __launch_bounds__(256) update2_k(
    float* __restrict__ x, const float* __restrict__ s, const int* __restrict__ cnt,
    const float* __restrict__ w2m, const float* __restrict__ b2m,
    const float* __restrict__ uw1 /*[128][64]*/, const float* __restrict__ ub1,
    const float* __restrict__ uw2 /*[64][64]*/, const float* __restrict__ ub2, int E) {
    __shared__ float mmb[EPB][DDIM + 1];
    __shared__ float hb[EPB][DDIM + 1];
    int lane = threadIdx.x & 63;
    int w = __builtin_amdgcn_readfirstlane((int)(threadIdx.x >> 6));
    int e = blockIdx.x * EPB + lane;
    bool ok = e < E;
    int eidx = ok ? e : 0;
    int j0 = w * 16;
    float degf = (float)cnt[eidx];
    float inv = 1.0f / fmaxf(degf, 1.0f);
    const float* sr = s + (size_t)eidx * DDIM;
    const float* xr = x + (size_t)eidx * DDIM;

    // mm
    float am[16];
    #pragma unroll
    for (int jj = 0; jj < 16; ++jj) am[jj] = degf * b2m[j0 + jj];
    #pragma unroll 2
    for (int c = 0; c < 16; ++c) {
        float4 v = ld4(sr + c * 4);
        float xv[4] = {v.x, v.y, v.z, v.w};
        #pragma unroll
        for (int kk = 0; kk < 4; ++kk) {
            const float* wk = w2m + (size_t)(c * 4 + kk) * DDIM + j0;
            #pragma unroll
            for (int jj = 0; jj < 16; ++jj) am[jj] = fmaf(xv[kk], wk[jj], am[jj]);
        }
    }
    #pragma unroll
    for (int jj = 0; jj < 16; ++jj) mmb[lane][j0 + jj] = am[jj] * inv;
    __syncthreads();

    // u-layer1: K=128 (mm from LDS, x from global)
    float ah[16];
    #pragma unroll
    for (int jj = 0; jj < 16; ++jj) ah[jj] = ub1[j0 + jj];
    #pragma unroll 4
    for (int k = 0; k < DDIM; ++k) {
        float mk = mmb[lane][k];
        const float* wk = uw1 + (size_t)k * DDIM + j0;
        #pragma unroll
        for (int jj = 0; jj < 16; ++jj) ah[jj] = fmaf(mk, wk[jj], ah[jj]);
    }
    #pragma unroll 2
    for (int c = 0; c < 16; ++c) {
        float4 v = ld4(xr + c * 4);
        float xv[4] = {v.x, v.y, v.z, v.w};
        #pragma unroll
        for (int kk = 0; kk < 4; ++kk) {
            const float* wk = uw1 + (size_t)(DDIM + c * 4 + kk) * DDIM + j0;
            #pragma unroll
            for (int jj = 0; jj < 16; ++jj) ah[jj] = fmaf(xv[kk], wk[jj], ah[jj]);
        }
    }
    #pragma unroll
    for (int jj = 0; jj < 16; ++jj) hb[lane][j0 + jj] = silu_f(ah[jj]);
    __syncthreads();

    // u-layer2
    float o[16];
    #pragma unroll
    for (int jj = 0; jj < 16; ++jj) o[jj] = ub2[j0 + jj];
    #pragma unroll 4
    for (int k = 0; k < DDIM; ++k) {
        float hk = hb[lane][k];
        const float* wk = uw2 + (size_t)k * DDIM + j0;
        #pragma unroll
        for (int jj = 0; jj < 16; ++jj) o[jj] = fmaf(hk, wk[jj], o[jj]);
    }
    if (ok) {
        float* xw = x + (size_t)e * DDIM + j0;
        #pragma unroll
        for (int q = 0; q < 4; ++q) {
            float4 xo = ld4(xw + q * 4);
            xo.x += o[q * 4 + 0];
            xo.y += o[q * 4 + 1];
            xo.z += o[q * 4 + 2];
            xo.w += o[q * 4 + 3];
            st4(xw + q * 4, xo);
        }
    }
}

// ---------------- pooling ----------------
static __device__ __forceinline__ int lower_bound_bb(const int* __restrict__ row,
                                                     const int* __restrict__ batch,
                                                     int E, int g) {
    int lo = 0, hi = E;
    while (lo < hi) {
        int m = (lo + hi) >> 1;
        if (batch[row[m]] < g) lo = m + 1; else hi = m;
    }
    return lo;
}

__global__ void __launch_bounds__(64) pool_partial_k(
    const float* __restrict__ x, const int* __restrict__ row, const int* __restrict__ batch,
    float* __restrict__ gfeat, int E) {
    int g = blockIdx.x, p = blockIdx.y, j = threadIdx.x;
    int s = lower_bound_bb(row, batch, E, g);
    int t = lower_bound_bb(row, batch, E, g + 1);
    int cnt = t - s;
    int chunk = (cnt + POOL_P - 1) / POOL_P;
    int e0 = s + p * chunk;
    int e1 = min(e0 + chunk, t);
    float sum = 0.f;
    for (int e = e0; e < e1; ++e) sum += x[(size_t)e * DDIM + j];
    if (e0 < e1)
        __hip_atomic_fetch_add(&gfeat[g * DDIM + j], sum, __ATOMIC_RELAXED,
                               __HIP_MEMORY_SCOPE_AGENT);
}

__global__ void __launch_bounds__(64) pool_final_k(
    const int* __restrict__ row, const int* __restrict__ batch,
    float* __restrict__ gfeat, int E) {
    int g = blockIdx.x, j = threadIdx.x;
    int s = lower_bound_bb(row, batch, E, g);
    int t = lower_bound_bb(row, batch, E, g + 1);
    float cnt = fmaxf((float)(t - s), 1.0f);
    gfeat[g * DDIM + j] /= cnt;
}

extern "C" void kernel_launch(void* const* d_in, const int* in_sizes, int n_in,
                              void* d_out, int out_size, void* d_ws, size_t ws_size,
                              hipStream_t stream) {
    (void)n_in; (void)out_size; (void)ws_size;
    const float* AF    = (const float*)d_in[0];
    const int*   batch = (const int*)d_in[3];
    const int*   edge_index      = (const int*)d_in[4];
    const int*   bond_edge_index = (const int*)d_in[5];
    const float* iw1 = (const float*)d_in[6];
    const float* ib1 = (const float*)d_in[7];
    const float* iw2 = (const float*)d_in[8];
    const float* ib2 = (const float*)d_in[9];
    const float* emb = (const float*)d_in[10];
    const float* mw1 = (const float*)d_in[11];
    const float* mb1 = (const float*)d_in[12];
    const float* mw2 = (const float*)d_in[13];
    const float* mb2 = (const float*)d_in[14];
    const float* uw1 = (const float*)d_in[15];
    const float* ub1 = (const float*)d_in[16];
    const float* uw2 = (const float*)d_in[17];
    const float* ub2 = (const float*)d_in[18];

    const int E  = in_sizes[4] / 2;
    const int BE = in_sizes[5] / 2;

    float* xout  = (float*)d_out;                 // [E,64]
    float* gfeat = xout + (size_t)E * DDIM;       // [16,64]

    // workspace layout
    char* w = (char*)d_ws;
    float* tt       = (float*)w;  w += sizeof(float) * NTYPES * DDIM;
    int*   cnt      = (int*)w;    w += sizeof(int) * E;
    int*   offs     = (int*)w;    w += sizeof(int) * (E + 1);
    int*   cursor   = (int*)w;    w += sizeof(int) * E;
    int*   bt       = (int*)w;    w += sizeof(int) * E;
    int*   srclist  = (int*)w;    w += sizeof(int) * BE;
    w = (char*)(((uintptr_t)w + 15) & ~(uintptr_t)15);
    float* pd       = (float*)w;  w += sizeof(float) * (size_t)E * DDIM;
    float* ps       = (float*)w;  w += sizeof(float) * (size_t)E * DDIM;

    const int* row  = edge_index;
    const int* col  = edge_index + E;
    const int* bsrc = bond_edge_index;
    const int* bdst = bond_edge_index + BE;

    const int EB = (E + EPB - 1) / EPB;   // edge blocks for wave-sliced kernels

    // CSR build (int atomics only)
    hipMemsetAsync(cnt, 0, (size_t)E * sizeof(int), stream);
    count_k<<<(BE + 255) / 256, 256, 0, stream>>>(bdst, cnt, BE);
    scan_k<<<1, 1024, 0, stream>>>(cnt, offs, E);
    hipMemcpyAsync(cursor, offs, (size_t)E * sizeof(int), hipMemcpyDeviceToDevice, stream);
    scatter_k<<<(BE + 255) / 256, 256, 0, stream>>>(bsrc, bdst, cursor, srclist, BE);

    bond_init_k<<<EB, 256, 0, stream>>>(AF, row, col, iw1, ib1, iw2, ib2, xout, bt, E);

    for (int l = 0; l < 2; ++l) {
        const float* w1l  = mw1 + (size_t)l * 192 * 64;
        const float* b1l  = mb1 + (size_t)l * DDIM;
        const float* w2l  = mw2 + (size_t)l * DDIM * DDIM;
        const float* b2l  = mb2 + (size_t)l * DDIM;
        const float* embl = emb + (size_t)l * NTYPES * DDIM;

        tt_k<<<NTYPES, 64, 0, stream>>>(embl, w1l, b1l, tt);
        proj_k<<<EB, 256, 0, stream>>>(xout, w1l, pd, ps, E);
        gather_k<<<(E * 4 + 255) / 256, 256, 0, stream>>>(pd, ps, tt, bt, offs, srclist, E);
        update2_k<<<EB, 256, 0, stream>>>(
            xout, pd, cnt, w2l, b2l,
            uw1 + (size_t)l * 128 * 64, ub1 + (size_t)l * DDIM,
            uw2 + (size_t)l * DDIM * DDIM, ub2 + (size_t)l * DDIM, E);
    }

    hipMemsetAsync(gfeat, 0, NGRAPHS * DDIM * sizeof(float), stream);
    dim3 pg(NGRAPHS, POOL_P);
    pool_partial_k<<<pg, 64, 0, stream>>>(xout, row, batch, gfeat, E);
    pool_final_k<<<NGRAPHS, 64, 0, stream>>>(row, batch, gfeat, E);
}

// Round 4
// 471.580 us; speedup vs baseline: 10.2522x; 1.2879x over previous
//
#include <hip/hip_runtime.h>
#include <cstdint>
#include <cstddef>

#define HDIM 128
#define DDIM 64
#define NTYPES 5
#define NGRAPHS 16
#define POOL_P 16
#define EPB 64   // edges per block (one per lane)

static __device__ __forceinline__ float silu_f(float v) {
    return v / (1.0f + __expf(-v));
}

static __device__ __forceinline__ float4 ld4(const float* p) {
    return *reinterpret_cast<const float4*>(p);
}

static __device__ __forceinline__ void st4(float* p, float4 v) {
    *reinterpret_cast<float4*>(p) = v;
}

static __device__ __forceinline__ float4 add4(float4 a, float4 b) {
    return make_float4(a.x + b.x, a.y + b.y, a.z + b.z, a.w + b.w);
}

static __device__ __forceinline__ void silu_acc4(float4& s, float4 v) {
    s.x += silu_f(v.x);
    s.y += silu_f(v.y);
    s.z += silu_f(v.z);
    s.w += silu_f(v.w);
}

// ---------------- CSR build ----------------
__global__ void __launch_bounds__(256) count_k(const int* __restrict__ bdst,
                                               int* __restrict__ cnt, int BE) {
    int i = blockIdx.x * 256 + threadIdx.x;
    if (i < BE)
        __hip_atomic_fetch_add(&cnt[bdst[i]], 1, __ATOMIC_RELAXED, __HIP_MEMORY_SCOPE_AGENT);
}

// pass 1: per-256-block sums
__global__ void __launch_bounds__(256) bsum_k(const int* __restrict__ cnt,
                                              int* __restrict__ bsum, int E) {
    __shared__ int red[256];
    int t = threadIdx.x;
    int i = blockIdx.x * 256 + t;
    red[t] = (i < E) ? cnt[i] : 0;
    __syncthreads();
    #pragma unroll
    for (int off = 128; off > 0; off >>= 1) {
        if (t < off) red[t] += red[t + off];
        __syncthreads();
    }
    if (t == 0) bsum[blockIdx.x] = red[0];
}

// pass 2: single block exclusive-scans block sums (NB <= 1024)
__global__ void __launch_bounds__(1024) bscan_k(const int* __restrict__ bsum,
                                                int* __restrict__ bpre, int NB) {
    __shared__ int sh[1024];
    int t = threadIdx.x;
    int v0 = (t < NB) ? bsum[t] : 0;
    sh[t] = v0;
    __syncthreads();
    for (int off = 1; off < 1024; off <<= 1) {
        int v = (t >= off) ? sh[t - off] : 0;
        __syncthreads();
        sh[t] += v;
        __syncthreads();
    }
    if (t < NB) bpre[t] = sh[t] - v0;
}

// pass 3: block-local exclusive scan + block prefix -> offs and cursor
__global__ void __launch_bounds__(256) offs_k(const int* __restrict__ cnt,
                                              const int* __restrict__ bpre,
                                              int* __restrict__ offs,
                                              int* __restrict__ cursor, int E) {
    __shared__ int sh[256];
    int t = threadIdx.x;
    int i = blockIdx.x * 256 + t;
    int v0 = (i < E) ? cnt[i] : 0;
    sh[t] = v0;
    __syncthreads();
    for (int off = 1; off < 256; off <<= 1) {
        int v = (t >= off) ? sh[t - off] : 0;
        __syncthreads();
        sh[t] += v;
        __syncthreads();
    }
    int ex = sh[t] - v0 + bpre[blockIdx.x];
    if (i < E) { offs[i] = ex; cursor[i] = ex; }
    if (i == E - 1) offs[E] = ex + v0;
}

__global__ void __launch_bounds__(256) scatter_k(const int* __restrict__ bsrc,
                                                 const int* __restrict__ bdst,
                                                 int* __restrict__ cursor,
                                                 int* __restrict__ srclist, int BE) {
    int i = blockIdx.x * 256 + threadIdx.x;
    if (i < BE) {
        int d = bdst[i];
        int p = __hip_atomic_fetch_add(&cursor[d], 1, __ATOMIC_RELAXED,
                                       __HIP_MEMORY_SCOPE_AGENT);
        srclist[p] = bsrc[i];
    }
}

// tt for BOTH layers: block = (l, type); tt[l][t][j] = mb1[l][j] + sum_k emb[l][t][k]*mw1[l][128+k][j]
__global__ void __launch_bounds__(64) tt2_k(const float* __restrict__ emb,
                                            const float* __restrict__ mw1,
                                            const float* __restrict__ mb1,
                                            float* __restrict__ tt) {
    int b = blockIdx.x;
    int l = b / NTYPES, t = b % NTYPES, j = threadIdx.x;
    const float* embl = emb + (size_t)l * NTYPES * DDIM + (size_t)t * DDIM;
    const float* w1 = mw1 + (size_t)l * 192 * DDIM;
    float s = mb1[l * DDIM + j];
    #pragma unroll 8
    for (int k = 0; k < DDIM; ++k)
        s = fmaf(embl[k], w1[(HDIM + k) * DDIM + j], s);
    tt[(size_t)b * DDIM + j] = s;
}

// ---------------- bond init + layer-0 proj fused ----------------
// block = 4 waves x 64 lanes; lane = edge; wave w owns output slice [16w,16w+16)
__global__ void __launch_bounds__(256) bond_init_proj_k(
    const float* __restrict__ AF, const int* __restrict__ row, const int* __restrict__ col,
    const float* __restrict__ w1 /*[256][64]*/, const float* __restrict__ b1,
    const float* __restrict__ w2 /*[64][64]*/, const float* __restrict__ b2,
    const float* __restrict__ w1p /*[192][64] layer0 mw1*/,
    float* __restrict__ x, int* __restrict__ bt,
    float* __restrict__ pd, float* __restrict__ ps, int E) {
    __shared__ float hbuf[EPB][DDIM + 1];
    int lane = threadIdx.x & 63;
    int w = __builtin_amdgcn_readfirstlane((int)(threadIdx.x >> 6));
    int e = blockIdx.x * EPB + lane;
    bool ok = e < E;
    int eidx = ok ? e : 0;
    const float* hi = AF + (size_t)row[eidx] * HDIM;
    const float* hj = AF + (size_t)col[eidx] * HDIM;
    int j0 = w * 16;

    if (w == 0) {
        float dot = 0.f, ni = 0.f, nj = 0.f;
        #pragma unroll 4
        for (int k = 0; k < HDIM; k += 4) {
            float4 a = ld4(hi + k), b = ld4(hj + k);
            dot += a.x * b.x + a.y * b.y + a.z * b.z + a.w * b.w;
            ni  += a.x * a.x + a.y * a.y + a.z * a.z + a.w * a.w;
            nj  += b.x * b.x + b.y * b.y + b.z * b.z + b.w * b.w;
        }
        float sim = dot / (fmaxf(sqrtf(ni), 1e-8f) * fmaxf(sqrtf(nj), 1e-8f));
        int t = 0;
        if (sim > 0.8f) t = 1;
        if (sim > 0.9f) t = 2;
        if (sim < 0.3f) t = 3;
        if (ok) bt[e] = t;
    }

    // L1: K=256
    float acc[16];
    #pragma unroll
    for (int jj = 0; jj < 16; ++jj) acc[jj] = b1[j0 + jj];
    #pragma unroll 2
    for (int c = 0; c < 32; ++c) {
        const float* sp = (c < 16) ? (hi + c * 8) : (hj + (c - 16) * 8);
        float4 v0 = ld4(sp), v1 = ld4(sp + 4);
        float xv[8] = {v0.x, v0.y, v0.z, v0.w, v1.x, v1.y, v1.z, v1.w};
        const float* wb = w1 + (size_t)(c * 8) * DDIM + j0;
        #pragma unroll
        for (int kk = 0; kk < 8; ++kk) {
            const float* wk = wb + (size_t)kk * DDIM;
            #pragma unroll
            for (int jj = 0; jj < 16; ++jj) acc[jj] = fmaf(xv[kk], wk[jj], acc[jj]);
        }
    }
    #pragma unroll
    for (int jj = 0; jj < 16; ++jj) hbuf[lane][j0 + jj] = silu_f(acc[jj]);
    __syncthreads();

    // L2: K=64 from LDS
    float o[16];
    #pragma unroll
    for (int jj = 0; jj < 16; ++jj) o[jj] = b2[j0 + jj];
    #pragma unroll 4
    for (int k = 0; k < DDIM; ++k) {
        float hk = hbuf[lane][k];
        const float* wk = w2 + (size_t)k * DDIM + j0;
        #pragma unroll
        for (int jj = 0; jj < 16; ++jj) o[jj] = fmaf(hk, wk[jj], o[jj]);
    }
    if (ok) {
        float* xr = x + (size_t)e * DDIM + j0;
        st4(xr + 0,  make_float4(o[0],  o[1],  o[2],  o[3]));
        st4(xr + 4,  make_float4(o[4],  o[5],  o[6],  o[7]));
        st4(xr + 8,  make_float4(o[8],  o[9],  o[10], o[11]));
        st4(xr + 12, make_float4(o[12], o[13], o[14], o[15]));
    }
    __syncthreads();            // all reads of hbuf (h) done
    #pragma unroll
    for (int jj = 0; jj < 16; ++jj) hbuf[lane][j0 + jj] = o[jj];   // now holds x row
    __syncthreads();

    // proj (layer 0): pd = x@W1[0:64], ps = x@W1[64:128], x from LDS
    float apd[16], aps[16];
    #pragma unroll
    for (int jj = 0; jj < 16; ++jj) { apd[jj] = 0.f; aps[jj] = 0.f; }
    #pragma unroll 4
    for (int k = 0; k < DDIM; ++k) {
        float xk = hbuf[lane][k];
        const float* wd = w1p + (size_t)k * DDIM + j0;
        const float* wsv = w1p + (size_t)(DDIM + k) * DDIM + j0;
        #pragma unroll
        for (int jj = 0; jj < 16; ++jj) {
            apd[jj] = fmaf(xk, wd[jj], apd[jj]);
            aps[jj] = fmaf(xk, wsv[jj], aps[jj]);
        }
    }
    if (ok) {
        float* pr = pd + (size_t)e * DDIM + j0;
        float* qr = ps + (size_t)e * DDIM + j0;
        st4(pr + 0,  make_float4(apd[0],  apd[1],  apd[2],  apd[3]));
        st4(pr + 4,  make_float4(apd[4],  apd[5],  apd[6],  apd[7]));
        st4(pr + 8,  make_float4(apd[8],  apd[9],  apd[10], apd[11]));
        st4(pr + 12, make_float4(apd[12], apd[13], apd[14], apd[15]));
        st4(qr + 0,  make_float4(aps[0],  aps[1],  aps[2],  aps[3]));
        st4(qr + 4,  make_float4(aps[4],  aps[5],  aps[6],  aps[7]));
        st4(qr + 8,  make_float4(aps[8],  aps[9],  aps[10], aps[11]));
        st4(qr + 12, make_float4(aps[12], aps[13], aps[14], aps[15]));
    }
}

// proj for layer 1 (x from global)
__global__ void __launch_bounds__(256) proj_k(const float* __restrict__ x,
                                              const float* __restrict__ w1 /*[192][64]*/,
                                              float* __restrict__ pd, float* __restrict__ ps,
                                              int E) {
    int lane = threadIdx.x & 63;
    int w = __builtin_amdgcn_readfirstlane((int)(threadIdx.x >> 6));
    int e = blockIdx.x * EPB + lane;
    bool ok = e < E;
    int eidx = ok ? e : 0;
    int j0 = w * 16;
    const float* xr = x + (size_t)eidx * DDIM;

    float apd[16], aps[16];
    #pragma unroll
    for (int jj = 0; jj < 16; ++jj) { apd[jj] = 0.f; aps[jj] = 0.f; }
    #pragma unroll 2
    for (int c = 0; c < 16; ++c) {
        float4 v = ld4(xr + c * 4);
        float xv[4] = {v.x, v.y, v.z, v.w};
        #pragma unroll
        for (int kk = 0; kk < 4; ++kk) {
            int k = c * 4 + kk;
            const float* wd = w1 + (size_t)k * DDIM + j0;
            const float* wsv = w1 + (size_t)(DDIM + k) * DDIM + j0;
            #pragma unroll
            for (int jj = 0; jj < 16; ++jj) {
                apd[jj] = fmaf(xv[kk], wd[jj], apd[jj]);
                aps[jj] = fmaf(xv[kk], wsv[jj], aps[jj]);
            }
        }
    }
    if (ok) {
        float* pr = pd + (size_t)e * DDIM + j0;
        float* qr = ps + (size_t)e * DDIM + j0;
        st4(pr + 0,  make_float4(apd[0],  apd[1],  apd[2],  apd[3]));
        st4(pr + 4,  make_float4(apd[4],  apd[5],  apd[6],  apd[7]));
        st4(pr + 8,  make_float4(apd[8],  apd[9],  apd[10], apd[11]));
        st4(pr + 12, make_float4(apd[12], apd[13], apd[14], apd[15]));
        st4(qr + 0,  make_float4(aps[0],  aps[1],  aps[2],  aps[3]));
        st4(qr + 4,  make_float4(aps[4],  aps[5],  aps[6],  aps[7]));
        st4(qr + 8,  make_float4(aps[8],  aps[9],  aps[10], aps[11]));
        st4(qr + 12, make_float4(aps[12], aps[13], aps[14], aps[15]));
    }
}

// ---------------- fused gather + mm + update ----------------
// P1: 4 thr/bond gather s -> LDS. P2: mm = (s@W2m + deg*b2m)/deg -> LDS.
// P3: h = silu([mm,x]@Wu1+bu1) -> LDS. P4: x += h@Wu2+bu2.
__global__ void __launch_bounds__(256) layer_k(
    float* __restrict__ x, const float* __restrict__ pd, const float* __restrict__ ps,
    const float* __restrict__ tt_l, const int* __restrict__ bt,
    const int* __restrict__ offs, const int* __restrict__ srclist,
    const int* __restrict__ cnt,
    const float* __restrict__ w2m, const float* __restrict__ b2m,
    const float* __restrict__ uw1 /*[128][64]*/, const float* __restrict__ ub1,
    const float* __restrict__ uw2 /*[64][64]*/, const float* __restrict__ ub2, int E) {
    __shared__ float sb[EPB][DDIM + 1];
    __shared__ float mb[EPB][DDIM + 1];
    int lane = threadIdx.x & 63;
    int w = __builtin_amdgcn_readfirstlane((int)(threadIdx.x >> 6));
    int e = blockIdx.x * EPB + lane;
    bool ok = e < E;
    int eidx = ok ? e : 0;
    int j0 = w * 16;

    // ---- P1: gather (thread = (d_local, q)) ----
    {
        int d_local = threadIdx.x >> 2, q = threadIdx.x & 3;
        int d = blockIdx.x * EPB + d_local;
        if (d < E) {
            int jq = q * 16;
            const float* pr = pd + (size_t)d * DDIM + jq;
            const float* tp = tt_l + (size_t)bt[d] * DDIM + jq;
            float4 b0 = add4(ld4(pr + 0),  ld4(tp + 0));
            float4 b1 = add4(ld4(pr + 4),  ld4(tp + 4));
            float4 b2 = add4(ld4(pr + 8),  ld4(tp + 8));
            float4 b3 = add4(ld4(pr + 12), ld4(tp + 12));
            float4 s0 = make_float4(0, 0, 0, 0), s1 = s0, s2 = s0, s3 = s0;
            int p0 = offs[d], p1 = offs[d + 1];
            for (int p = p0; p < p1; ++p) {
                const float* sr = ps + (size_t)srclist[p] * DDIM + jq;
                float4 v0 = ld4(sr + 0), v1 = ld4(sr + 4);
                float4 v2 = ld4(sr + 8), v3 = ld4(sr + 12);
                silu_acc4(s0, add4(b0, v0));
                silu_acc4(s1, add4(b1, v1));
                silu_acc4(s2, add4(b2, v2));
                silu_acc4(s3, add4(b3, v3));
            }
            st4(&sb[d_local][jq + 0],  s0);
            st4(&sb[d_local][jq + 4],  s1);
            st4(&sb[d_local][jq + 8],  s2);
            st4(&sb[d_local][jq + 12], s3);
        }
    }
    __syncthreads();

    // ---- P2: mm ----
    float degf = (float)cnt[eidx];
    float inv = 1.0f / fmaxf(degf, 1.0f);
    {
        float am[16];
        #pragma unroll
        for (int jj = 0; jj < 16; ++jj) am[jj] = degf * b2m[j0 + jj];
        #pragma unroll 4
        for (int k = 0; k < DDIM; ++k) {
            float sk = sb[lane][k];
            const float* wk = w2m + (size_t)k * DDIM + j0;
            #pragma unroll
            for (int jj = 0; jj < 16; ++jj) am[jj] = fmaf(sk, wk[jj], am[jj]);
        }
        #pragma unroll
        for (int jj = 0; jj < 16; ++jj) mb[lane][j0 + jj] = am[jj] * inv;
    }
    __syncthreads();

    // ---- P3: u-layer1 (mm from LDS, x from global) ----
    const float* xr = x + (size_t)eidx * DDIM;
    {
        float ah[16];
        #pragma unroll
        for (int jj = 0; jj < 16; ++jj) ah[jj] = ub1[j0 + jj];
        #pragma unroll 4
        for (int k = 0; k < DDIM; ++k) {
            float mk = mb[lane][k];
            const float* wk = uw1 + (size_t)k * DDIM + j0;
            #pragma unroll
            for (int jj = 0; jj < 16; ++jj) ah[jj] = fmaf(mk, wk[jj], ah[jj]);
        }
        #pragma unroll 2
        for (int c = 0; c < 16; ++c) {
            float4 v = ld4(xr + c * 4);
            float xv[4] = {v.x, v.y, v.z, v.w};
            #pragma unroll
            for (int kk = 0; kk < 4; ++kk) {
                const float* wk = uw1 + (size_t)(DDIM + c * 4 + kk) * DDIM + j0;
                #pragma unroll
                for (int jj = 0; jj < 16; ++jj) ah[jj] = fmaf(xv[kk], wk[jj], ah[jj]);
            }
        }
        #pragma unroll
        for (int jj = 0; jj < 16; ++jj) sb[lane][j0 + jj] = silu_f(ah[jj]);
    }
    __syncthreads();

    // ---- P4: u-layer2 + residual ----
    {
        float o[16];
        #pragma unroll
        for (int jj = 0; jj < 16; ++jj) o[jj] = ub2[j0 + jj];
        #pragma unroll 4
        for (int k = 0; k < DDIM; ++k) {
            float hk = sb[lane][k];
            const float* wk = uw2 + (size_t)k * DDIM + j0;
            #pragma unroll
            for (int jj = 0; jj < 16; ++jj) o[jj] = fmaf(hk, wk[jj], o[jj]);
        }
        if (ok) {
            float* xw = x + (size_t)e * DDIM + j0;
            #pragma unroll
            for (int q = 0; q < 4; ++q) {
                float4 xo = ld4(xw + q * 4);
                xo.x += o[q * 4 + 0];
                xo.y += o[q * 4 + 1];
                xo.z += o[q * 4 + 2];
                xo.w += o[q * 4 + 3];
                st4(xw + q * 4, xo);
            }
        }
    }
}

// ---------------- pooling ----------------
static __device__ __forceinline__ int lower_bound_bb(const int* __restrict__ row,
                                                     const int* __restrict__ batch,
                                                     int E, int g) {
    int lo = 0, hi = E;
    while (lo < hi) {
        int m = (lo + hi) >> 1;
        if (batch[row[m]] < g) lo = m + 1; else hi = m;
    }
    return lo;
}

__global__ void __launch_bounds__(64) pool_partial_k(
    const float* __restrict__ x, const int* __restrict__ row, const int* __restrict__ batch,
    float* __restrict__ gfeat, int E) {
    int g = blockIdx.x, p = blockIdx.y, j = threadIdx.x;
    int s = lower_bound_bb(row, batch, E, g);
    int t = lower_bound_bb(row, batch, E, g + 1);
    int cnt = t - s;
    int chunk = (cnt + POOL_P - 1) / POOL_P;
    int e0 = s + p * chunk;
    int e1 = min(e0 + chunk, t);
    float sum = 0.f;
    for (int e = e0; e < e1; ++e) sum += x[(size_t)e * DDIM + j];
    if (e0 < e1)
        __hip_atomic_fetch_add(&gfeat[g * DDIM + j], sum, __ATOMIC_RELAXED,
                               __HIP_MEMORY_SCOPE_AGENT);
}

__global__ void __launch_bounds__(64) pool_final_k(
    const int* __restrict__ row, const int* __restrict__ batch,
    float* __restrict__ gfeat, int E) {
    int g = blockIdx.x, j = threadIdx.x;
    int s = lower_bound_bb(row, batch, E, g);
    int t = lower_bound_bb(row, batch, E, g + 1);
    float cnt = fmaxf((float)(t - s), 1.0f);
    gfeat[g * DDIM + j] /= cnt;
}

extern "C" void kernel_launch(void* const* d_in, const int* in_sizes, int n_in,
                              void* d_out, int out_size, void* d_ws, size_t ws_size,
                              hipStream_t stream) {
    (void)n_in; (void)out_size; (void)ws_size;
    const float* AF    = (const float*)d_in[0];
    const int*   batch = (const int*)d_in[3];
    const int*   edge_index      = (const int*)d_in[4];
    const int*   bond_edge_index = (const int*)d_in[5];
    const float* iw1 = (const float*)d_in[6];
    const float* ib1 = (const float*)d_in[7];
    const float* iw2 = (const float*)d_in[8];
    const float* ib2 = (const float*)d_in[9];
    const float* emb = (const float*)d_in[10];
    const float* mw1 = (const float*)d_in[11];
    const float* mb1 = (const float*)d_in[12];
    const float* mw2 = (const float*)d_in[13];
    const float* mb2 = (const float*)d_in[14];
    const float* uw1 = (const float*)d_in[15];
    const float* ub1 = (const float*)d_in[16];
    const float* uw2 = (const float*)d_in[17];
    const float* ub2 = (const float*)d_in[18];

    const int E  = in_sizes[4] / 2;
    const int BE = in_sizes[5] / 2;
    const int NB = (E + 255) / 256;       // scan blocks (<=1024)
    const int EB = (E + EPB - 1) / EPB;   // edge blocks for wave-sliced kernels

    float* xout  = (float*)d_out;                 // [E,64]
    float* gfeat = xout + (size_t)E * DDIM;       // [16,64]

    // workspace layout
    char* w = (char*)d_ws;
    float* tt       = (float*)w;  w += sizeof(float) * 2 * NTYPES * DDIM;
    int*   cnt      = (int*)w;    w += sizeof(int) * E;
    int*   offs     = (int*)w;    w += sizeof(int) * (E + 1);
    int*   cursor   = (int*)w;    w += sizeof(int) * E;
    int*   bt       = (int*)w;    w += sizeof(int) * E;
    int*   bsum     = (int*)w;    w += sizeof(int) * 1024;
    int*   bpre     = (int*)w;    w += sizeof(int) * 1024;
    int*   srclist  = (int*)w;    w += sizeof(int) * BE;
    w = (char*)(((uintptr_t)w + 15) & ~(uintptr_t)15);
    float* pd       = (float*)w;  w += sizeof(float) * (size_t)E * DDIM;
    float* ps       = (float*)w;  w += sizeof(float) * (size_t)E * DDIM;

    const int* row  = edge_index;
    const int* col  = edge_index + E;
    const int* bsrc = bond_edge_index;
    const int* bdst = bond_edge_index + BE;

    // CSR build
    hipMemsetAsync(cnt, 0, (size_t)E * sizeof(int), stream);
    count_k<<<(BE + 255) / 256, 256, 0, stream>>>(bdst, cnt, BE);
    bsum_k<<<NB, 256, 0, stream>>>(cnt, bsum, E);
    bscan_k<<<1, 1024, 0, stream>>>(bsum, bpre, NB);
    offs_k<<<NB, 256, 0, stream>>>(cnt, bpre, offs, cursor, E);
    scatter_k<<<(BE + 255) / 256, 256, 0, stream>>>(bsrc, bdst, cursor, srclist, BE);

    // bond-type embeddings for both layers
    tt2_k<<<2 * NTYPES, 64, 0, stream>>>(emb, mw1, mb1, tt);

    // bond init + layer-0 proj
    bond_init_proj_k<<<EB, 256, 0, stream>>>(AF, row, col, iw1, ib1, iw2, ib2,
                                             mw1 /* layer 0 */, xout, bt, pd, ps, E);

    for (int l = 0; l < 2; ++l) {
        if (l > 0)
            proj_k<<<EB, 256, 0, stream>>>(xout, mw1 + (size_t)l * 192 * 64, pd, ps, E);
        layer_k<<<EB, 256, 0, stream>>>(
            xout, pd, ps, tt + (size_t)l * NTYPES * DDIM, bt, offs, srclist, cnt,
            mw2 + (size_t)l * DDIM * DDIM, mb2 + (size_t)l * DDIM,
            uw1 + (size_t)l * 128 * 64, ub1 + (size_t)l * DDIM,
            uw2 + (size_t)l * DDIM * DDIM, ub2 + (size_t)l * DDIM, E);
    }

    hipMemsetAsync(gfeat, 0, NGRAPHS * DDIM * sizeof(float), stream);
    dim3 pg(NGRAPHS, POOL_P);
    pool_partial_k<<<pg, 64, 0, stream>>>(xout, row, batch, gfeat, E);
    pool_final_k<<<NGRAPHS, 64, 0, stream>>>(row, batch, gfeat, E);
}